// Round 14
// baseline (238.701 us; speedup 1.0000x reference)
//
#include <hip/hip_runtime.h>

#define N_PTS 32768
#define M_Q   8192
#define C_F   256
#define GS    32
#define NC    (GS * GS * GS)          // 32768 cells per side
#define TOTP  (2 * N_PTS)             // 65536 points
#define TOTQ  (2 * M_Q)               // 16384 queries
#define LOC   (-4.4f)
#define CWID  (8.8f / GS)             // 0.275
#define INVW  (GS / 8.8f)
#define MARG  2e-4f
#define INF_F __int_as_float(0x7f800000)
#define MAXI  0x7fffffff

__device__ __forceinline__ float rn_mul(float a, float b) { return __fmul_rn(a, b); }
__device__ __forceinline__ float rn_add(float a, float b) { return __fadd_rn(a, b); }

__device__ __forceinline__ int cellco(float v) {
    int c = (int)floorf((v - LOC) * INVW);
    return c < 0 ? 0 : (c > GS - 1 ? GS - 1 : c);
}

// exact lexicographic (d,i) insert into running top-2 pair
__device__ __forceinline__ void ins_lex(float d, int i, float& b1, int& j1,
                                        float& b2, int& j2) {
    bool lt1 = (d < b1) || (d == b1 && i < j1);
    bool lt2 = (d < b2) || (d == b2 && i < j2);
    b2 = lt1 ? b1 : (lt2 ? d : b2);
    j2 = lt1 ? j1 : (lt2 ? i : j2);
    b1 = lt1 ? d : b1;
    j1 = lt1 ? i : j1;
}
__device__ __forceinline__ void ins_lex2(float d, int i, float& b2, int& j2) {
    bool lt2 = (d < b2) || (d == b2 && i < j2);
    b2 = lt2 ? d : b2;
    j2 = lt2 ? i : j2;
}

// K1: per-point cell id + histogram
__global__ __launch_bounds__(256) void build_cells(
    const float* __restrict__ c0, const float* __restrict__ c1,
    int* __restrict__ counts, int* __restrict__ cid)
{
    int t = blockIdx.x * 256 + threadIdx.x;     // 0..65535
    int side = t >> 15, n = t & (N_PTS - 1);
    const float* c = side ? c1 : c0;
    float x = c[n * 3], y = c[n * 3 + 1], z = c[n * 3 + 2];
    int g = side * NC + (cellco(z) * GS + cellco(y)) * GS + cellco(x);
    cid[t] = g;
    atomicAdd(&counts[g], 1);
}

// K1q: per-query cell id + histogram
__global__ __launch_bounds__(256) void build_qcells(
    const float* __restrict__ s0, const float* __restrict__ s1,
    int* __restrict__ qcounts, int* __restrict__ qcid)
{
    int t = blockIdx.x * 256 + threadIdx.x;     // 0..16383
    int side = t >> 13, q = t & (M_Q - 1);
    const float* s = side ? s1 : s0;
    float x = s[q * 3], y = s[q * 3 + 1], z = s[q * 3 + 2];
    int g = side * NC + (cellco(z) * GS + cellco(y)) * GS + cellco(x);
    qcid[t] = g;
    atomicAdd(&qcounts[g], 1);
}

// K2: per-256-block exclusive scan, emit block sums
__global__ __launch_bounds__(256) void scan1(const int* __restrict__ counts,
                                             int* __restrict__ starts,
                                             int* __restrict__ bsum)
{
    __shared__ int s[256];
    int b = blockIdx.x, tid = threadIdx.x;
    int v = counts[b * 256 + tid];
    s[tid] = v;
    __syncthreads();
    for (int o = 1; o < 256; o <<= 1) {
        int u = (tid >= o) ? s[tid - o] : 0;
        __syncthreads();
        s[tid] += u;
        __syncthreads();
    }
    starts[b * 256 + tid] = s[tid] - v;   // exclusive
    if (tid == 255) bsum[b] = s[255];
}

// K3: exclusive scan of the 256 block sums (single block)
__global__ __launch_bounds__(256) void scan2(int* __restrict__ bsum) {
    __shared__ int s[256];
    int tid = threadIdx.x;
    int v = bsum[tid];
    s[tid] = v;
    __syncthreads();
    for (int o = 1; o < 256; o <<= 1) {
        int u = (tid >= o) ? s[tid - o] : 0;
        __syncthreads();
        s[tid] += u;
        __syncthreads();
    }
    bsum[tid] = s[tid] - v;
}

// K4: add block offsets + sentinel
__global__ __launch_bounds__(256) void scan3(int* __restrict__ starts,
                                             const int* __restrict__ bsum,
                                             int sentinel)
{
    int b = blockIdx.x, tid = threadIdx.x;
    starts[b * 256 + tid] += bsum[b];
    if (b == 0 && tid == 0) starts[256 * 256] = sentinel;
}

// K5: scatter points into cell-sorted pool
__global__ __launch_bounds__(256) void scatter(
    const float* __restrict__ c0, const float* __restrict__ c1,
    const int* __restrict__ cid, const int* __restrict__ starts,
    int* __restrict__ counts, float4* __restrict__ pts4, int* __restrict__ pidx)
{
    int t = blockIdx.x * 256 + threadIdx.x;
    int side = t >> 15, n = t & (N_PTS - 1);
    const float* c = side ? c1 : c0;
    float x = c[n * 3], y = c[n * 3 + 1], z = c[n * 3 + 2];
    float b2 = rn_add(rn_add(rn_mul(x, x), rn_mul(y, y)), rn_mul(z, z));
    int g = cid[t];
    int pos = starts[g] + (atomicSub(&counts[g], 1) - 1);
    pts4[pos] = make_float4(x, y, z, b2);
    pidx[pos] = n;
}

// K5q: scatter query ids into cell-sorted order
__global__ __launch_bounds__(256) void qscatter(
    const int* __restrict__ qcid, const int* __restrict__ qstarts,
    int* __restrict__ qcounts, int* __restrict__ qsorted)
{
    int t = blockIdx.x * 256 + threadIdx.x;     // 0..16383
    int g = qcid[t];
    int pos = qstarts[g] + (atomicSub(&qcounts[g], 1) - 1);
    qsorted[pos] = t;
}

// K6: 8 sorted queries per 64-thread block; 8 lanes/query expanding-shell
// exact 2-NN (identical logic to the verified r13 kernel) + fused gather.
__global__ __launch_bounds__(64) void query2nn(
    const float* __restrict__ src, const float* __restrict__ tgt,
    const float* __restrict__ sc0, const float* __restrict__ sc1,
    const float4* __restrict__ pts4, const int* __restrict__ pidx,
    const int* __restrict__ starts, const int* __restrict__ qsorted,
    float* __restrict__ out)
{
    __shared__ int sres[8];
    __shared__ int sqid[8];

    int tid = threadIdx.x, sub = tid & 7, g = tid >> 3;
    int qpos = blockIdx.x * 8 + g;              // 0..16383 (sorted order)
    int qid  = qsorted[qpos];
    int side = qid >> 13, q = qid & (M_Q - 1);
    const float* sc = side ? sc1 : sc0;

    float ax = sc[q * 3], ay = sc[q * 3 + 1], az = sc[q * 3 + 2];
    float a2 = rn_add(rn_add(rn_mul(ax, ax), rn_mul(ay, ay)), rn_mul(az, az));
    int cx = cellco(ax), cy = cellco(ay), cz = cellco(az);
    const int* st = starts + side * NC;

    float d1 = INF_F, d2 = INF_F;
    int   i1 = MAXI,  i2 = MAXI;
    int   gi2 = MAXI;

    auto visit = [&](int xx, int yy, int zz) {
        int c = (zz * GS + yy) * GS + xx;
        int s0 = st[c], s1 = st[c + 1];
        for (int j = s0 + sub; j < s1; j += 8) {
            float4 p = pts4[j];
            float dot = __builtin_fmaf(az, p.z,
                         __builtin_fmaf(ay, p.y, rn_mul(ax, p.x)));
            float dd = __builtin_fmaf(-2.0f, dot, rn_add(a2, p.w));
            ins_lex(dd, pidx[j], d1, i1, d2, i2);
        }
    };

    for (int r = 0; r < GS; ++r) {
        if (r == 0) {
            visit(cx, cy, cz);
        } else {
            int xlo = max(cx - r, 0), xhi = min(cx + r, GS - 1);
            int ylo = max(cy - r, 0), yhi = min(cy + r, GS - 1);
            int zlo2 = max(cz - r + 1, 0), zhi2 = min(cz + r - 1, GS - 1);
            int ylo2 = max(cy - r + 1, 0), yhi2 = min(cy + r - 1, GS - 1);
            if (cz - r >= 0)
                for (int yy = ylo; yy <= yhi; ++yy)
                    for (int xx = xlo; xx <= xhi; ++xx) visit(xx, yy, cz - r);
            if (cz + r < GS)
                for (int yy = ylo; yy <= yhi; ++yy)
                    for (int xx = xlo; xx <= xhi; ++xx) visit(xx, yy, cz + r);
            if (cy - r >= 0)
                for (int zz = zlo2; zz <= zhi2; ++zz)
                    for (int xx = xlo; xx <= xhi; ++xx) visit(xx, cy - r, zz);
            if (cy + r < GS)
                for (int zz = zlo2; zz <= zhi2; ++zz)
                    for (int xx = xlo; xx <= xhi; ++xx) visit(xx, cy + r, zz);
            if (cx - r >= 0)
                for (int zz = zlo2; zz <= zhi2; ++zz)
                    for (int yy = ylo2; yy <= yhi2; ++yy) visit(cx - r, yy, zz);
            if (cx + r < GS)
                for (int zz = zlo2; zz <= zhi2; ++zz)
                    for (int yy = ylo2; yy <= yhi2; ++yy) visit(cx + r, yy, zz);
        }
        // group merge into temps (privates stay pure)
        float t1 = d1, t2 = d2; int u1 = i1, u2 = i2;
#pragma unroll
        for (int mk = 1; mk < 8; mk <<= 1) {
            float o1 = __shfl_xor(t1, mk); int p1 = __shfl_xor(u1, mk);
            float o2 = __shfl_xor(t2, mk); int p2 = __shfl_xor(u2, mk);
            ins_lex(o1, p1, t1, u1, t2, u2);
            ins_lex2(o2, p2, t2, u2);
        }
        gi2 = u2;
        // stop bound: min distance to active faces of examined cell-cube
        float bnd = INF_F;
        if (cx - r > 0)      bnd = fminf(bnd, ax - (LOC + (cx - r) * CWID));
        if (cx + r < GS - 1) bnd = fminf(bnd, (LOC + (cx + r + 1) * CWID) - ax);
        if (cy - r > 0)      bnd = fminf(bnd, ay - (LOC + (cy - r) * CWID));
        if (cy + r < GS - 1) bnd = fminf(bnd, (LOC + (cy + r + 1) * CWID) - ay);
        if (cz - r > 0)      bnd = fminf(bnd, az - (LOC + (cz - r) * CWID));
        if (cz + r < GS - 1) bnd = fminf(bnd, (LOC + (cz + r + 1) * CWID) - az);
        if (bnd == INF_F) break;                    // entire grid examined
        if (t2 < bnd * bnd - MARG) break;           // rigorous exact stop
    }

    if (sub == 0) { sres[g] = gi2; sqid[g] = qid; }
    __syncthreads();

    // fused gather: 8 rows of 256 floats; 64 threads -> 1 float4 each per row
#pragma unroll 2
    for (int rg = 0; rg < 8; ++rg) {
        int qq = sqid[rg];
        int sd = qq >> 13;
        const float* feats = sd ? tgt : src;
        int row = sres[rg];
        const float4* sp = (const float4*)(feats + (size_t)row * C_F);
        float4* dp = (float4*)(out + (size_t)qq * C_F);
        dp[tid] = sp[tid];
    }
}

extern "C" void kernel_launch(void* const* d_in, const int* in_sizes, int n_in,
                              void* d_out, int out_size, void* d_ws, size_t ws_size,
                              hipStream_t stream) {
    const float* src  = (const float*)d_in[0];
    const float* tgt  = (const float*)d_in[1];
    const float* c0   = (const float*)d_in[2];  // src_coords   (N,3)
    const float* c1   = (const float*)d_in[3];  // tgt_coords   (N,3)
    const float* sh0  = (const float*)d_in[4];  // src_shortcut (M,3)
    const float* sh1  = (const float*)d_in[5];  // tgt_shortcut (M,3)
    float* out = (float*)d_out;

    char* w = (char*)d_ws;
    float4* pts4    = (float4*)(w);                      // 1,048,576
    int*    pidx    = (int*)(w + 1048576);               //   262,144
    int*    cid     = (int*)(w + 1310720);               //   262,144
    int*    counts  = (int*)(w + 1572864);               //   262,144
    int*    starts  = (int*)(w + 1835008);               //   262,148 (65537)
    int*    bsum    = (int*)(w + 2097280);               //     1,024
    int*    qcid    = (int*)(w + 2098304);               //    65,536
    int*    qcounts = (int*)(w + 2163840);               //   262,144
    int*    qstarts = (int*)(w + 2425984);               //   262,148 (65537)
    int*    qbsum   = (int*)(w + 2688256);               //     1,024
    int*    qsorted = (int*)(w + 2689280);               //    65,536  -> 2,754,816 total

    hipMemsetAsync(counts, 0, (size_t)TOTP * sizeof(int), stream);
    hipMemsetAsync(qcounts, 0, (size_t)TOTP * sizeof(int), stream);

    // point grid
    hipLaunchKernelGGL(build_cells, dim3(TOTP / 256), dim3(256), 0, stream,
                       c0, c1, counts, cid);
    hipLaunchKernelGGL(scan1, dim3(TOTP / 256), dim3(256), 0, stream,
                       counts, starts, bsum);
    hipLaunchKernelGGL(scan2, dim3(1), dim3(256), 0, stream, bsum);
    hipLaunchKernelGGL(scan3, dim3(TOTP / 256), dim3(256), 0, stream,
                       starts, bsum, TOTP);
    hipLaunchKernelGGL(scatter, dim3(TOTP / 256), dim3(256), 0, stream,
                       c0, c1, cid, starts, counts, pts4, pidx);

    // query sort (same counting-sort machinery)
    hipLaunchKernelGGL(build_qcells, dim3(TOTQ / 256), dim3(256), 0, stream,
                       sh0, sh1, qcounts, qcid);
    hipLaunchKernelGGL(scan1, dim3(TOTP / 256), dim3(256), 0, stream,
                       qcounts, qstarts, qbsum);
    hipLaunchKernelGGL(scan2, dim3(1), dim3(256), 0, stream, qbsum);
    hipLaunchKernelGGL(scan3, dim3(TOTP / 256), dim3(256), 0, stream,
                       qstarts, qbsum, TOTQ);
    hipLaunchKernelGGL(qscatter, dim3(TOTQ / 256), dim3(256), 0, stream,
                       qcid, qstarts, qcounts, qsorted);

    // sorted shell-walk + gather
    hipLaunchKernelGGL(query2nn, dim3(TOTQ / 8), dim3(64), 0, stream,
                       src, tgt, sh0, sh1, pts4, pidx, starts, qsorted, out);
}

// Round 15
// 99.934 us; speedup vs baseline: 2.3886x; 2.3886x over previous
//
#include <hip/hip_runtime.h>

#define N_PTS 32768
#define M_Q   8192
#define C_F   256
#define GS    32
#define NC    (GS * GS * GS)          // 32768 cells per side
#define TOTP  (2 * N_PTS)             // 65536 points
#define TOTQ  (2 * M_Q)               // 16384 queries
#define LOC   (-4.4f)
#define CWID  (8.8f / GS)             // 0.275
#define INVW  (GS / 8.8f)
#define MARG  2e-4f
#define INF_F __int_as_float(0x7f800000)
#define MAXI  0x7fffffff

__device__ __forceinline__ float rn_mul(float a, float b) { return __fmul_rn(a, b); }
__device__ __forceinline__ float rn_add(float a, float b) { return __fadd_rn(a, b); }

__device__ __forceinline__ int cellco(float v) {
    int c = (int)floorf((v - LOC) * INVW);
    return c < 0 ? 0 : (c > GS - 1 ? GS - 1 : c);
}

// exact lexicographic (d,i) insert into running top-2 pair
__device__ __forceinline__ void ins_lex(float d, int i, float& b1, int& j1,
                                        float& b2, int& j2) {
    bool lt1 = (d < b1) || (d == b1 && i < j1);
    bool lt2 = (d < b2) || (d == b2 && i < j2);
    b2 = lt1 ? b1 : (lt2 ? d : b2);
    j2 = lt1 ? j1 : (lt2 ? i : j2);
    b1 = lt1 ? d : b1;
    j1 = lt1 ? i : j1;
}
__device__ __forceinline__ void ins_lex2(float d, int i, float& b2, int& j2) {
    bool lt2 = (d < b2) || (d == b2 && i < j2);
    b2 = lt2 ? d : b2;
    j2 = lt2 ? i : j2;
}

// K1: per-point cell id + histogram
__global__ __launch_bounds__(256) void build_cells(
    const float* __restrict__ c0, const float* __restrict__ c1,
    int* __restrict__ counts, int* __restrict__ cid)
{
    int t = blockIdx.x * 256 + threadIdx.x;     // 0..65535
    int side = t >> 15, n = t & (N_PTS - 1);
    const float* c = side ? c1 : c0;
    float x = c[n * 3], y = c[n * 3 + 1], z = c[n * 3 + 2];
    int g = side * NC + (cellco(z) * GS + cellco(y)) * GS + cellco(x);
    cid[t] = g;
    atomicAdd(&counts[g], 1);
}

// K2: per-256-block exclusive scan, emit block sums
__global__ __launch_bounds__(256) void scan1(const int* __restrict__ counts,
                                             int* __restrict__ starts,
                                             int* __restrict__ bsum)
{
    __shared__ int s[256];
    int b = blockIdx.x, tid = threadIdx.x;
    int v = counts[b * 256 + tid];
    s[tid] = v;
    __syncthreads();
    for (int o = 1; o < 256; o <<= 1) {
        int u = (tid >= o) ? s[tid - o] : 0;
        __syncthreads();
        s[tid] += u;
        __syncthreads();
    }
    starts[b * 256 + tid] = s[tid] - v;   // exclusive
    if (tid == 255) bsum[b] = s[255];
}

// K3: exclusive scan of the 256 block sums (single block)
__global__ __launch_bounds__(256) void scan2(int* __restrict__ bsum) {
    __shared__ int s[256];
    int tid = threadIdx.x;
    int v = bsum[tid];
    s[tid] = v;
    __syncthreads();
    for (int o = 1; o < 256; o <<= 1) {
        int u = (tid >= o) ? s[tid - o] : 0;
        __syncthreads();
        s[tid] += u;
        __syncthreads();
    }
    bsum[tid] = s[tid] - v;
}

// K4: add block offsets + sentinel
__global__ __launch_bounds__(256) void scan3(int* __restrict__ starts,
                                             const int* __restrict__ bsum)
{
    int b = blockIdx.x, tid = threadIdx.x;
    starts[b * 256 + tid] += bsum[b];
    if (b == 0 && tid == 0) starts[TOTP] = TOTP;   // sentinel
}

// K5: scatter points into cell-sorted pool
__global__ __launch_bounds__(256) void scatter(
    const float* __restrict__ c0, const float* __restrict__ c1,
    const int* __restrict__ cid, const int* __restrict__ starts,
    int* __restrict__ counts, float4* __restrict__ pts4, int* __restrict__ pidx)
{
    int t = blockIdx.x * 256 + threadIdx.x;
    int side = t >> 15, n = t & (N_PTS - 1);
    const float* c = side ? c1 : c0;
    float x = c[n * 3], y = c[n * 3 + 1], z = c[n * 3 + 2];
    float b2 = rn_add(rn_add(rn_mul(x, x), rn_mul(y, y)), rn_mul(z, z));
    int g = cid[t];
    int pos = starts[g] + (atomicSub(&counts[g], 1) - 1);
    pts4[pos] = make_float4(x, y, z, b2);
    pidx[pos] = n;
}

// K6: ONE WAVE PER QUERY. Lanes stride over the cells of expanding cubes
// (Chebyshev-skip of the already-scanned inner cube => each point inserted
// exactly once). Exact-numpy distance chain + lex top-2 (verified r13 logic).
__global__ __launch_bounds__(64) void query2nn(
    const float* __restrict__ src, const float* __restrict__ tgt,
    const float* __restrict__ sc0, const float* __restrict__ sc1,
    const float4* __restrict__ pts4, const int* __restrict__ pidx,
    const int* __restrict__ starts, float* __restrict__ out)
{
    int lane = threadIdx.x;
    int qid  = blockIdx.x;                   // 0..16383
    int side = qid >> 13, q = qid & (M_Q - 1);
    const float* sc = side ? sc1 : sc0;

    float ax = sc[q * 3], ay = sc[q * 3 + 1], az = sc[q * 3 + 2];
    float a2 = rn_add(rn_add(rn_mul(ax, ax), rn_mul(ay, ay)), rn_mul(az, az));
    int cx = cellco(ax), cy = cellco(ay), cz = cellco(az);
    const int* st = starts + side * NC;

    float d1 = INF_F, d2 = INF_F;            // per-lane privates (disjoint cells)
    int   i1 = MAXI,  i2 = MAXI;
    int   best2 = MAXI;

    const int rs[9] = {0, 1, 2, 3, 5, 8, 13, 21, 31};
    int rprev = -1;

#pragma unroll 1
    for (int si = 0; si < 9; ++si) {
        int r = rs[si];
        int S = 2 * r + 1, S2 = S * S, tot = S * S2;
        for (int k = lane; k < tot; k += 64) {
            int dz = k / S2;
            int rem = k - dz * S2;
            int dy = rem / S;
            int dx = rem - dy * S;
            dx -= r; dy -= r; dz -= r;
            int adx = dx < 0 ? -dx : dx;
            int ady = dy < 0 ? -dy : dy;
            int adz = dz < 0 ? -dz : dz;
            int ch = max(adx, max(ady, adz));
            if (ch <= rprev) continue;                       // already scanned
            int xx = cx + dx, yy = cy + dy, zz = cz + dz;
            if ((unsigned)xx >= GS || (unsigned)yy >= GS || (unsigned)zz >= GS)
                continue;
            int c = (zz * GS + yy) * GS + xx;
            int s0 = st[c], s1 = st[c + 1];
            for (int j = s0; j < s1; ++j) {
                float4 p = pts4[j];
                float dot = __builtin_fmaf(az, p.z,
                             __builtin_fmaf(ay, p.y, rn_mul(ax, p.x)));
                float dd = __builtin_fmaf(-2.0f, dot, rn_add(a2, p.w));
                ins_lex(dd, pidx[j], d1, i1, d2, i2);
            }
        }
        rprev = r;

        // full 64-lane merge into temps (privates stay pure)
        float t1 = d1, t2 = d2; int u1 = i1, u2 = i2;
#pragma unroll
        for (int mk = 1; mk < 64; mk <<= 1) {
            float o1 = __shfl_xor(t1, mk); int p1 = __shfl_xor(u1, mk);
            float o2 = __shfl_xor(t2, mk); int p2 = __shfl_xor(u2, mk);
            ins_lex(o1, p1, t1, u1, t2, u2);
            ins_lex2(o2, p2, t2, u2);
        }
        best2 = u2;

        // stop bound: min distance to active faces of the scanned cube
        float bnd = INF_F;
        if (cx - r > 0)      bnd = fminf(bnd, ax - (LOC + (cx - r) * CWID));
        if (cx + r < GS - 1) bnd = fminf(bnd, (LOC + (cx + r + 1) * CWID) - ax);
        if (cy - r > 0)      bnd = fminf(bnd, ay - (LOC + (cy - r) * CWID));
        if (cy + r < GS - 1) bnd = fminf(bnd, (LOC + (cy + r + 1) * CWID) - ay);
        if (cz - r > 0)      bnd = fminf(bnd, az - (LOC + (cz - r) * CWID));
        if (cz + r < GS - 1) bnd = fminf(bnd, (LOC + (cz + r + 1) * CWID) - az);
        if (bnd == INF_F) break;                    // entire grid examined
        if (t2 < bnd * bnd - MARG) break;           // rigorous exact stop
    }

    // fused gather: merged result is uniform across lanes after the butterfly
    const float* feats = side ? tgt : src;
    const float4* sp = (const float4*)(feats + (size_t)best2 * C_F);
    float4* dp = (float4*)(out + (size_t)qid * C_F);
    dp[lane] = sp[lane];
}

extern "C" void kernel_launch(void* const* d_in, const int* in_sizes, int n_in,
                              void* d_out, int out_size, void* d_ws, size_t ws_size,
                              hipStream_t stream) {
    const float* src  = (const float*)d_in[0];
    const float* tgt  = (const float*)d_in[1];
    const float* c0   = (const float*)d_in[2];  // src_coords   (N,3)
    const float* c1   = (const float*)d_in[3];  // tgt_coords   (N,3)
    const float* sh0  = (const float*)d_in[4];  // src_shortcut (M,3)
    const float* sh1  = (const float*)d_in[5];  // tgt_shortcut (M,3)
    float* out = (float*)d_out;

    char* w = (char*)d_ws;
    float4* pts4   = (float4*)(w);                       // 1,048,576
    int*    pidx   = (int*)(w + 1048576);                //   262,144
    int*    cid    = (int*)(w + 1310720);                //   262,144
    int*    counts = (int*)(w + 1572864);                //   262,144
    int*    starts = (int*)(w + 1835008);                //   262,148 (65537)
    int*    bsum   = (int*)(w + 2097280);                //     1,024

    hipMemsetAsync(counts, 0, (size_t)TOTP * sizeof(int), stream);

    hipLaunchKernelGGL(build_cells, dim3(TOTP / 256), dim3(256), 0, stream,
                       c0, c1, counts, cid);
    hipLaunchKernelGGL(scan1, dim3(TOTP / 256), dim3(256), 0, stream,
                       counts, starts, bsum);
    hipLaunchKernelGGL(scan2, dim3(1), dim3(256), 0, stream, bsum);
    hipLaunchKernelGGL(scan3, dim3(TOTP / 256), dim3(256), 0, stream,
                       starts, bsum);
    hipLaunchKernelGGL(scatter, dim3(TOTP / 256), dim3(256), 0, stream,
                       c0, c1, cid, starts, counts, pts4, pidx);
    hipLaunchKernelGGL(query2nn, dim3(TOTQ), dim3(64), 0, stream,
                       src, tgt, sh0, sh1, pts4, pidx, starts, out);
}